// Round 11
// baseline (241.291 us; speedup 1.0000x reference)
//
#include <hip/hip_runtime.h>
#include <hip/hip_cooperative_groups.h>
#include <cstdint>
#include <cstddef>

namespace cg = cooperative_groups;

#define D_MODEL 1024
#define D_STATE 16
#define D_CONV  4
#define D_INNER 2048
#define SEQ     2048
#define NCHUNK  128
#define CLEN    16
#define NGRP    8
#define GCH     16
#define LN_EPS  1e-5f

typedef unsigned short ushort_t;
typedef __attribute__((ext_vector_type(8))) short short8;
typedef __attribute__((ext_vector_type(4))) float f32x4;

__device__ __forceinline__ ushort_t f2bf(float x) {
  union { float f; uint32_t u; } v; v.f = x;
  uint32_t r = (v.u + 0x7fffu + ((v.u >> 16) & 1u)) >> 16;
  return (ushort_t)r;
}
__device__ __forceinline__ float bf2f(ushort_t u) {
  union { uint32_t x; float f; } v; v.x = ((uint32_t)u) << 16; return v.f;
}

__device__ __forceinline__ void async16(void* lds, const void* g) {
  __builtin_amdgcn_global_load_lds(
      (const __attribute__((address_space(1))) unsigned int*)g,
      (__attribute__((address_space(3))) unsigned int*)lds, 16, 0, 0);
}

__device__ __forceinline__ float softplus_f(float x) {
  if (x > 20.f) return x;
  if (x < -20.f) return __expf(x);
  return __logf(1.f + __expf(x));
}

// da[n] = g1^(n+1), log-depth
__device__ __forceinline__ void dapow(float g1, float* da) {
  float g2 = g1 * g1, g4 = g2 * g2, g8 = g4 * g4;
  #pragma unroll
  for (int n = 0; n < 16; n++) {
    int e = n + 1;
    float v = (e & 1) ? g1 : 1.f;
    if (e & 2) v *= g2;
    if (e & 4) v *= g4;
    if (e & 8) v *= g8;
    da[n] = v;
  }
}

// ---------------- prep: weight cvt (f32->bf16, x4 vec) + LayerNorm ----------------
__global__ __launch_bounds__(256) void prep_kernel(const float* __restrict__ x,
                                                   const float* __restrict__ g,
                                                   const float* __restrict__ b,
                                                   const float* __restrict__ inw,
                                                   const float* __restrict__ outw,
                                                   const float* __restrict__ xpw,
                                                   ushort_t* __restrict__ xn_bf,
                                                   ushort_t* __restrict__ inw_bf,
                                                   ushort_t* __restrict__ outw_bf,
                                                   ushort_t* __restrict__ xpw_bf) {
  int blk = blockIdx.x;
  if (blk < SEQ) {
    int row = blk;
    const float4* xr = (const float4*)(x + (size_t)row * D_MODEL);
    float4 v = xr[threadIdx.x];
    float s  = v.x + v.y + v.z + v.w;
    float ss = v.x * v.x + v.y * v.y + v.z * v.z + v.w * v.w;
    #pragma unroll
    for (int o = 32; o; o >>= 1) { s += __shfl_down(s, o); ss += __shfl_down(ss, o); }
    __shared__ float sbuf[8], ssbuf[8];
    int wid = threadIdx.x >> 6, lane = threadIdx.x & 63;
    if (lane == 0) { sbuf[wid] = s; ssbuf[wid] = ss; }
    __syncthreads();
    if (threadIdx.x == 0) {
      float t = 0.f, t2 = 0.f;
      for (int i = 0; i < 4; i++) { t += sbuf[i]; t2 += ssbuf[i]; }
      float mu = t / D_MODEL;
      sbuf[4] = mu;
      ssbuf[4] = rsqrtf(t2 / D_MODEL - mu * mu + LN_EPS);
    }
    __syncthreads();
    float mu = sbuf[4], inv = ssbuf[4];
    float4 gv = ((const float4*)g)[threadIdx.x];
    float4 bv = ((const float4*)b)[threadIdx.x];
    ushort_t o4[4];
    o4[0] = f2bf((v.x - mu) * inv * gv.x + bv.x);
    o4[1] = f2bf((v.y - mu) * inv * gv.y + bv.y);
    o4[2] = f2bf((v.z - mu) * inv * gv.z + bv.z);
    o4[3] = f2bf((v.w - mu) * inv * gv.w + bv.w);
    *(ushort4*)&xn_bf[(size_t)row * D_MODEL + threadIdx.x * 4] =
        make_ushort4(o4[0], o4[1], o4[2], o4[3]);
  } else {
    int idx = ((blk - SEQ) * 256 + threadIdx.x) * 4;
    const int n1 = 2 * D_INNER * D_MODEL;
    const int n2 = D_MODEL * D_INNER;
    const int n3 = 64 * D_INNER;
    const float* src; ushort_t* dst; int j;
    if (idx < n1) { src = inw; dst = inw_bf; j = idx; }
    else if (idx < n1 + n2) { src = outw; dst = outw_bf; j = idx - n1; }
    else if (idx < n1 + n2 + n3) {
      j = idx - n1 - n2;
      if (j < 33 * D_INNER) { src = xpw; dst = xpw_bf; }
      else {
        *(ushort4*)&xpw_bf[j] = make_ushort4(0, 0, 0, 0);
        return;
      }
    } else return;
    float4 v = *(const float4*)&src[j];
    *(ushort4*)&dst[j] = make_ushort4(f2bf(v.x), f2bf(v.y), f2bf(v.z), f2bf(v.w));
  }
}

// ---------------- unified pipelined MFMA GEMM, NT layout ----------------
// EPI: 0=bf16 out, 1=f32+residual, 3=xp partial (stride 33, c<33).
template <int BM, int BN, int KDIM, int EPI, int NBUF, int KSPLIT, int MINW>
__global__ __launch_bounds__(256, MINW) void gemm_pipe(const ushort_t* __restrict__ A,
                                                       const ushort_t* __restrict__ B,
                                                       void* __restrict__ Cout,
                                                       const float* __restrict__ R,
                                                       int N) {
  constexpr int KT = KDIM / 32 / KSPLIT;
  constexpr int K2 = KDIM * 2;
  constexpr int IA = BM / 64, IB = BN / 64;
  constexpr int S  = IA + IB;
  constexpr int W  = (NBUF - 2) * S;
  constexpr int WTM = BM / 2, WTN = BN / 2;
  constexpr int MREP = WTM / 16, NREP = WTN / 16;
  __shared__ __align__(16) ushort_t As[NBUF][BM * 32];
  __shared__ __align__(16) ushort_t Bs[NBUF][BN * 32];

  const int nwg = gridDim.x * gridDim.y;
  int bid = blockIdx.y * gridDim.x + blockIdx.x;
  int swz = (bid & 7) * (nwg >> 3) + (bid >> 3);
  int bn = swz % gridDim.x, bm = swz / gridDim.x;
  int ks = 0;
  if constexpr (KSPLIT > 1) { ks = bn; bn = 0; }
  const int tid = threadIdx.x, wid = tid >> 6, lane = tid & 63;
  const int wm = wid >> 1, wn = wid & 1;
  const int row0A = bm * BM, row0B = bn * BN;
  const size_t kbase = (size_t)ks * KT * 64;

  const char* gA[IA];
  const char* gB[IB];
  #pragma unroll
  for (int i = 0; i < IA; i++) {
    int o = i * 4096 + tid * 16;
    int r = o >> 6, src = (o & 63) ^ ((r & 3) << 4);
    gA[i] = (const char*)A + (size_t)(row0A + r) * K2 + src + kbase;
  }
  #pragma unroll
  for (int i = 0; i < IB; i++) {
    int o = i * 4096 + tid * 16;
    int r = o >> 6, src = (o & 63) ^ ((r & 3) << 4);
    gB[i] = (const char*)B + (size_t)(row0B + r) * K2 + src + kbase;
  }
  const int ldsW = wid * 1024;

  auto STAGE = [&](int bb, int kt) {
    int kb = kt * 64;
    #pragma unroll
    for (int i = 0; i < IA; i++)
      async16((char*)&As[bb][0] + i * 4096 + ldsW, gA[i] + kb);
    #pragma unroll
    for (int i = 0; i < IB; i++)
      async16((char*)&Bs[bb][0] + i * 4096 + ldsW, gB[i] + kb);
  };

  #pragma unroll
  for (int p = 0; p < NBUF - 1; p++) STAGE(p, p);

  int offA[MREP], offB[NREP];
  #pragma unroll
  for (int m = 0; m < MREP; m++) {
    int row = wm * WTM + m * 16 + (lane & 15);
    offA[m] = row * 64 + ((((lane >> 4)) ^ (row & 3)) << 4);
  }
  #pragma unroll
  for (int n = 0; n < NREP; n++) {
    int row = wn * WTN + n * 16 + (lane & 15);
    offB[n] = row * 64 + ((((lane >> 4)) ^ (row & 3)) << 4);
  }

  f32x4 acc[MREP][NREP] = {};
  int cur = 0;
  for (int kt = 0; kt < KT; kt++) {
    if (kt < KT - 1) {
      if constexpr (W == 4)       asm volatile("s_waitcnt vmcnt(4)" ::: "memory");
      else if constexpr (W == 6)  asm volatile("s_waitcnt vmcnt(6)" ::: "memory");
      else if constexpr (W == 8)  asm volatile("s_waitcnt vmcnt(8)" ::: "memory");
      else if constexpr (W == 12) asm volatile("s_waitcnt vmcnt(12)" ::: "memory");
      else                        asm volatile("s_waitcnt vmcnt(0)" ::: "memory");
    } else {
      asm volatile("s_waitcnt vmcnt(0)" ::: "memory");
    }
    __builtin_amdgcn_s_barrier();
    __builtin_amdgcn_sched_barrier(0);
    const char* Ab = (const char*)&As[cur][0];
    const char* Bb = (const char*)&Bs[cur][0];
    short8 af[MREP], bf[NREP];
    #pragma unroll
    for (int m = 0; m < MREP; m++) af[m] = *(const short8*)(Ab + offA[m]);
    #pragma unroll
    for (int n = 0; n < NREP; n++) bf[n] = *(const short8*)(Bb + offB[n]);
    if (kt + NBUF - 1 < KT) {
      int b2 = cur + NBUF - 1; if (b2 >= NBUF) b2 -= NBUF;
      STAGE(b2, kt + NBUF - 1);
    }
    __builtin_amdgcn_s_setprio(1);
    #pragma unroll
    for (int m = 0; m < MREP; m++)
      #pragma unroll
      for (int n = 0; n < NREP; n++)
        acc[m][n] = __builtin_amdgcn_mfma_f32_16x16x32_bf16(af[m], bf[n], acc[m][n], 0, 0, 0);
    __builtin_amdgcn_s_setprio(0);
    cur++; if (cur == NBUF) cur = 0;
  }

  #pragma unroll
  for (int m = 0; m < MREP; m++)
    #pragma unroll
    for (int n = 0; n < NREP; n++) {
      int r0 = row0A + wm * WTM + m * 16 + ((lane >> 4) << 2);
      int c  = row0B + wn * WTN + n * 16 + (lane & 15);
      #pragma unroll
      for (int q = 0; q < 4; q++) {
        if constexpr (EPI == 0) {
          ((ushort_t*)Cout)[(size_t)(r0 + q) * N + c] = f2bf(acc[m][n][q]);
        } else if constexpr (EPI == 1) {
          size_t idx = (size_t)(r0 + q) * N + c;
          ((float*)Cout)[idx] = acc[m][n][q] + R[idx];
        } else {
          if (c < 33)
            ((float*)Cout)[((size_t)ks * SEQ + r0 + q) * 33 + c] = acc[m][n][q];
        }
      }
    }
}

// ---------------- depthwise causal conv + SiLU, 4 t per block ----------------
__global__ __launch_bounds__(256) void conv_silu_kernel(const ushort_t* __restrict__ xz_bf,
                                                        const float* __restrict__ cw,
                                                        const float* __restrict__ cb,
                                                        ushort_t* __restrict__ xs_bf) {
  const int t0 = blockIdx.x * 4;
  const int d0 = threadIdx.x * 8;
  short8 win[7];
  #pragma unroll
  for (int j = 0; j < 7; j++) {
    int tt = t0 - 3 + j;
    if (tt >= 0) win[j] = *(const short8*)&xz_bf[(size_t)tt * (2 * D_INNER) + d0];
    else         win[j] = (short8)0;
  }
  float4 w[8];
  float  cbv[8];
  #pragma unroll
  for (int j = 0; j < 8; j++) { w[j] = ((const float4*)cw)[d0 + j]; cbv[j] = cb[d0 + j]; }
  #pragma unroll
  for (int q = 0; q < 4; q++) {
    short8 o8;
    #pragma unroll
    for (int j = 0; j < 8; j++) {
      float acc = cbv[j]
                + bf2f((ushort_t)win[q][j])     * w[j].x
                + bf2f((ushort_t)win[q + 1][j]) * w[j].y
                + bf2f((ushort_t)win[q + 2][j]) * w[j].z
                + bf2f((ushort_t)win[q + 3][j]) * w[j].w;
      float sg = 1.f / (1.f + __expf(-acc));
      o8[j] = (short)f2bf(acc * sg);
    }
    *(short8*)&xs_bf[(size_t)(t0 + q) * D_INNER + d0] = o8;
  }
}

// ---------------- cooperative fused scan: pass1 -> combineA -> pass2 ----------------
// grid (NCHUNK, 4) = 512 blocks = 2/CU co-resident. xs & delta stay in registers
// across the grid syncs; B/C/dr LDS persists.
__global__ __launch_bounds__(256, 2) void coop_scan(const ushort_t* __restrict__ xs_bf,
                                                    const float* __restrict__ xpp,
                                                    const ushort_t* __restrict__ xz_bf,
                                                    const float* __restrict__ dt_w,
                                                    const float* __restrict__ dt_b,
                                                    const float* __restrict__ A_log,
                                                    const float* __restrict__ Dp,
                                                    ushort_t* __restrict__ Hp,
                                                    float* __restrict__ Sd,
                                                    ushort_t* __restrict__ Hl,
                                                    float* __restrict__ Slocp,
                                                    ushort_t* __restrict__ Hgtot,
                                                    float* __restrict__ Sgtot,
                                                    ushort_t* __restrict__ y_bf) {
  cg::grid_group grid = cg::this_grid();
  const int c = blockIdx.x;
  const int d0 = blockIdx.y * 512 + threadIdx.x;
  const size_t stride = (size_t)D_INNER * 16;
  __shared__ float Bsh[CLEN][16], Csh[CLEN][16], drs[CLEN], Ash[16];
  {
    int t = threadIdx.x >> 4, n = threadIdx.x & 15;
    const size_t P = (size_t)SEQ * 33;
    size_t rb = (size_t)(c * CLEN + t) * 33;
    float sB = 0.f, sC = 0.f;
    #pragma unroll
    for (int k = 0; k < 8; k++) {
      sB += xpp[k * P + rb + 1 + n];
      sC += xpp[k * P + rb + 17 + n];
    }
    Bsh[t][n] = sB;
    Csh[t][n] = sC;
    if (threadIdx.x < CLEN) {
      size_t rr = (size_t)(c * CLEN + threadIdx.x) * 33;
      float sD = 0.f;
      #pragma unroll
      for (int k = 0; k < 8; k++) sD += xpp[k * P + rr];
      drs[threadIdx.x] = sD;
    } else if (threadIdx.x < CLEN + 16) {
      int n2 = threadIdx.x - CLEN;
      Ash[n2] = -__expf(A_log[n2]);
    }
  }
  __syncthreads();
  bool fastA = true;
  #pragma unroll
  for (int n = 0; n < 16; n++) fastA = fastA && (fabsf(Ash[n] + (float)(n + 1)) < 1e-4f * (n + 1));
  float dw[2] = {dt_w[d0], dt_w[d0 + 256]};
  float db[2] = {dt_b[d0], dt_b[d0 + 256]};

  // -------- phase 1: local chunk scan (keep xs & delta in regs) --------
  float xva[CLEN][2], dla[CLEN][2];
  {
    size_t tb = (size_t)(c * CLEN) * D_INNER + d0;
    #pragma unroll
    for (int t = 0; t < CLEN; t++) {
      xva[t][0] = bf2f(xs_bf[tb]);
      xva[t][1] = bf2f(xs_bf[tb + 256]);
      tb += D_INNER;
    }
  }
  #pragma unroll
  for (int t = 0; t < CLEN; t++) {
    float drt = drs[t];
    dla[t][0] = softplus_f(drt * dw[0] + db[0]);
    dla[t][1] = softplus_f(drt * dw[1] + db[1]);
  }
  {
    float h[2][16] = {};
    float S[2] = {0.f, 0.f};
    #pragma unroll
    for (int t = 0; t < CLEN; t++) {
      float bb[16];
      *(float4*)&bb[0]  = *(const float4*)&Bsh[t][0];
      *(float4*)&bb[4]  = *(const float4*)&Bsh[t][4];
      *(float4*)&bb[8]  = *(const float4*)&Bsh[t][8];
      *(float4*)&bb[12] = *(const float4*)&Bsh[t][12];
      #pragma unroll
      for (int u = 0; u < 2; u++) {
        float delta = dla[t][u];
        S[u] += delta;
        float w = delta * xva[t][u];
        if (fastA) {
          float da[16];
          dapow(__expf(-delta), da);
          #pragma unroll
          for (int n = 0; n < 16; n++) h[u][n] = da[n] * h[u][n] + w * bb[n];
        } else {
          #pragma unroll
          for (int n = 0; n < 16; n++) h[u][n] = __expf(delta * Ash[n]) * h[u][n] + w * bb[n];
        }
      }
    }
    #pragma unroll
    for (int u = 0; u < 2; u++) {
      int d = d0 + u * 256;
      size_t base = ((size_t)c * D_INNER + d) * 16;
      short8 p0, p1;
      #pragma unroll
      for (int n = 0; n < 8; n++) { p0[n] = (short)f2bf(h[u][n]); p1[n] = (short)f2bf(h[u][8 + n]); }
      *(short8*)&Hp[base] = p0;
      *(short8*)&Hp[base + 8] = p1;
      Sd[(size_t)c * D_INNER + d] = S[u];
    }
  }
  grid.sync();

  // -------- phase 2: combineA (flat remap over groups) --------
  {
    int flat = (blockIdx.y * gridDim.x + blockIdx.x) * 256 + (int)threadIdx.x;
    for (int it = flat; it < NGRP * D_INNER * 16; it += 512 * 256) {
      int g2 = it >> 15, idx = it & 32767;
      int d = idx >> 4, n = idx & 15;
      float An = Ash[n];
      float hh = 0.f, SS = 0.f;
      #pragma unroll 4
      for (int j = 0; j < GCH; j++) {
        int c2 = g2 * GCH + j;
        Hl[(size_t)c2 * stride + idx] = f2bf(hh);
        if (n == 0) Slocp[(size_t)c2 * D_INNER + d] = SS;
        float Sc = Sd[(size_t)c2 * D_INNER + d];
        hh = __expf(An * Sc) * hh + bf2f(Hp[(size_t)c2 * stride + idx]);
        SS += Sc;
      }
      Hgtot[(size_t)g2 * stride + idx] = f2bf(hh);
      if (n == 0) Sgtot[(size_t)g2 * D_INNER + d] = SS;
    }
  }
  grid.sync();

  // -------- phase 3: pass2 with group-prefix fold + gating --------
  float Dd[2] = {Dp[d0], Dp[d0 + 256]};
  int g8 = c >> 4;
  float h[2][16];
  #pragma unroll
  for (int u = 0; u < 2; u++) {
    int d = d0 + u * 256;
    float G[16];
    #pragma unroll
    for (int n = 0; n < 16; n++) G[n] = 0.f;
    for (int g = 0; g < g8; g++) {
      float Sg = Sgtot[(size_t)g * D_INNER + d];
      size_t gb = (size_t)g * stride + (size_t)d * 16;
      short8 hg0 = *(const short8*)&Hgtot[gb];
      short8 hg1 = *(const short8*)&Hgtot[gb + 8];
      if (fastA) {
        float pw[16];
        dapow(__expf(-Sg), pw);
        #pragma unroll
        for (int n = 0; n < 8; n++) {
          G[n]     = pw[n]     * G[n]     + bf2f((ushort_t)hg0[n]);
          G[8 + n] = pw[8 + n] * G[8 + n] + bf2f((ushort_t)hg1[n]);
        }
      } else {
        #pragma unroll
        for (int n = 0; n < 8; n++) {
          G[n]     = __expf(Ash[n] * Sg)     * G[n]     + bf2f((ushort_t)hg0[n]);
          G[8 + n] = __expf(Ash[8 + n] * Sg) * G[8 + n] + bf2f((ushort_t)hg1[n]);
        }
      }
    }
    size_t hb = ((size_t)c * D_INNER + d) * 16;
    float Slp = Slocp[(size_t)c * D_INNER + d];
    short8 hl0 = *(const short8*)&Hl[hb];
    short8 hl1 = *(const short8*)&Hl[hb + 8];
    float hl[16];
    #pragma unroll
    for (int n = 0; n < 8; n++) {
      hl[n] = bf2f((ushort_t)hl0[n]); hl[8 + n] = bf2f((ushort_t)hl1[n]);
    }
    if (fastA) {
      float pw[16];
      dapow(__expf(-Slp), pw);
      #pragma unroll
      for (int n = 0; n < 16; n++) h[u][n] = hl[n] + pw[n] * G[n];
    } else {
      #pragma unroll
      for (int n = 0; n < 16; n++) h[u][n] = hl[n] + __expf(Ash[n] * Slp) * G[n];
    }
  }
  size_t zb = (size_t)(c * CLEN) * (2 * D_INNER) + D_INNER + d0;
  float zv[2] = {bf2f(xz_bf[zb]), bf2f(xz_bf[zb + 256])};
  #pragma unroll
  for (int t = 0; t < CLEN; t++) {
    float nz[2] = {0.f, 0.f};
    if (t + 1 < CLEN) {
      nz[0] = bf2f(xz_bf[zb + 2 * D_INNER]);
      nz[1] = bf2f(xz_bf[zb + 2 * D_INNER + 256]);
    }
    float bb[16], cc[16];
    *(float4*)&bb[0]  = *(const float4*)&Bsh[t][0];
    *(float4*)&bb[4]  = *(const float4*)&Bsh[t][4];
    *(float4*)&bb[8]  = *(const float4*)&Bsh[t][8];
    *(float4*)&bb[12] = *(const float4*)&Bsh[t][12];
    *(float4*)&cc[0]  = *(const float4*)&Csh[t][0];
    *(float4*)&cc[4]  = *(const float4*)&Csh[t][4];
    *(float4*)&cc[8]  = *(const float4*)&Csh[t][8];
    *(float4*)&cc[12] = *(const float4*)&Csh[t][12];
    size_t ti = (size_t)(c * CLEN + t);
    #pragma unroll
    for (int u = 0; u < 2; u++) {
      float delta = dla[t][u];
      float w = delta * xva[t][u];
      float y = 0.f;
      if (fastA) {
        float da[16];
        dapow(__expf(-delta), da);
        #pragma unroll
        for (int n = 0; n < 16; n++) {
          h[u][n] = da[n] * h[u][n] + w * bb[n];
          y += h[u][n] * cc[n];
        }
      } else {
        #pragma unroll
        for (int n = 0; n < 16; n++) {
          h[u][n] = __expf(delta * Ash[n]) * h[u][n] + w * bb[n];
          y += h[u][n] * cc[n];
        }
      }
      float z = zv[u];
      float sz = z / (1.f + __expf(-z));
      float out = (y + xva[t][u] * Dd[u]) * sz;
      y_bf[ti * D_INNER + d0 + u * 256] = f2bf(out);
    }
    zv[0] = nz[0]; zv[1] = nz[1];
    zb += 2 * D_INNER;
  }
}

// ---------------- launch ----------------
extern "C" void kernel_launch(void* const* d_in, const int* in_sizes, int n_in,
                              void* d_out, int out_size, void* d_ws, size_t ws_size,
                              hipStream_t stream) {
  const float* x      = (const float*)d_in[0];
  const float* ln_g   = (const float*)d_in[1];
  const float* ln_b   = (const float*)d_in[2];
  const float* in_w   = (const float*)d_in[3];
  const float* conv_w = (const float*)d_in[4];
  const float* conv_b = (const float*)d_in[5];
  const float* xproj_w= (const float*)d_in[6];
  const float* dt_w   = (const float*)d_in[7];
  const float* dt_b   = (const float*)d_in[8];
  const float* A_log  = (const float*)d_in[9];
  const float* Dp     = (const float*)d_in[10];
  const float* out_w  = (const float*)d_in[11];
  float* out = (float*)d_out;

  char* ws = (char*)d_ws;
  size_t off = 0;
  auto alloc = [&](size_t bytes) { char* p = ws + off; off += (bytes + 255) & ~(size_t)255; return p; };
  ushort_t* xz_bf   = (ushort_t*)alloc((size_t)SEQ * 2 * D_INNER * 2);
  ushort_t* xn_bf   = (ushort_t*)alloc((size_t)SEQ * D_MODEL * 2);
  ushort_t* inw_bf  = (ushort_t*)alloc((size_t)2 * D_INNER * D_MODEL * 2);
  ushort_t* outw_bf = (ushort_t*)alloc((size_t)D_MODEL * D_INNER * 2);
  ushort_t* xpw_bf  = (ushort_t*)alloc((size_t)64 * D_INNER * 2);
  ushort_t* xs_bf   = (ushort_t*)alloc((size_t)SEQ * D_INNER * 2);
  float*    xp_part = (float*)   alloc((size_t)8 * SEQ * 33 * 4);
  ushort_t* Hp      = (ushort_t*)alloc((size_t)NCHUNK * D_INNER * 16 * 2);
  ushort_t* Hl      = (ushort_t*)alloc((size_t)NCHUNK * D_INNER * 16 * 2);
  float*    Sd      = (float*)   alloc((size_t)NCHUNK * D_INNER * 4);
  float*    Slocp   = (float*)   alloc((size_t)NCHUNK * D_INNER * 4);
  ushort_t* Hgtot   = (ushort_t*)alloc((size_t)NGRP * D_INNER * 16 * 2);
  float*    Sgtot   = (float*)   alloc((size_t)NGRP * D_INNER * 4);
  ushort_t* y_bf    = (ushort_t*)alloc((size_t)SEQ * D_INNER * 2);
  (void)ws_size;

  const int ncvt4 = (2 * D_INNER * D_MODEL + D_MODEL * D_INNER + 64 * D_INNER) / 4;
  prep_kernel<<<SEQ + (ncvt4 + 255) / 256, 256, 0, stream>>>(
      x, ln_g, ln_b, in_w, out_w, xproj_w, xn_bf, inw_bf, outw_bf, xpw_bf);
  // in_proj: M=2048 N=4096 K=1024 (128x128, NBUF=4, 64KB, 512 blocks = 2/CU) — R8 config
  gemm_pipe<128, 128, D_MODEL, 0, 4, 1, 2><<<dim3(2 * D_INNER / 128, SEQ / 128), 256, 0, stream>>>(
      xn_bf, inw_bf, xz_bf, nullptr, 2 * D_INNER);
  conv_silu_kernel<<<SEQ / 4, 256, 0, stream>>>(xz_bf, conv_w, conv_b, xs_bf);
  // x_proj: K-split x8 (64x64, NBUF=6) — R8 config
  gemm_pipe<64, 64, D_INNER, 3, 6, 8, 2><<<dim3(8, SEQ / 64), 256, 0, stream>>>(
      xs_bf, xpw_bf, xp_part, nullptr, 64);
  // fused cooperative scan (pass1 + combineA + pass2)
  {
    void* cargs[] = {(void*)&xs_bf, (void*)&xp_part, (void*)&xz_bf, (void*)&dt_w, (void*)&dt_b,
                     (void*)&A_log, (void*)&Dp, (void*)&Hp, (void*)&Sd, (void*)&Hl, (void*)&Slocp,
                     (void*)&Hgtot, (void*)&Sgtot, (void*)&y_bf};
    hipLaunchCooperativeKernel((void*)coop_scan, dim3(NCHUNK, D_INNER / 512), dim3(256, 1, 1),
                               cargs, 0, stream);
  }
  // out_proj + residual: M=2048 N=1024 K=2048 (64x64, NBUF=6) — R8 config
  gemm_pipe<64, 64, D_INNER, 1, 6, 1, 2><<<dim3(D_MODEL / 64, SEQ / 64), 256, 0, stream>>>(
      y_bf, outw_bf, out, x, D_MODEL);
}

// Round 12
// 118.662 us; speedup vs baseline: 2.0334x; 2.0334x over previous
//
#include <hip/hip_runtime.h>
#include <cstdint>
#include <cstddef>

#define D_MODEL 1024
#define D_STATE 16
#define D_CONV  4
#define D_INNER 2048
#define SEQ     2048
#define NCHUNK  128
#define CLEN    16
#define NGRP    8
#define GCH     16
#define LN_EPS  1e-5f

typedef unsigned short ushort_t;
typedef __attribute__((ext_vector_type(8))) short short8;
typedef __attribute__((ext_vector_type(4))) float f32x4;

__device__ __forceinline__ ushort_t f2bf(float x) {
  union { float f; uint32_t u; } v; v.f = x;
  uint32_t r = (v.u + 0x7fffu + ((v.u >> 16) & 1u)) >> 16;
  return (ushort_t)r;
}
__device__ __forceinline__ float bf2f(ushort_t u) {
  union { uint32_t x; float f; } v; v.x = ((uint32_t)u) << 16; return v.f;
}

__device__ __forceinline__ void async16(void* lds, const void* g) {
  __builtin_amdgcn_global_load_lds(
      (const __attribute__((address_space(1))) unsigned int*)g,
      (__attribute__((address_space(3))) unsigned int*)lds, 16, 0, 0);
}

__device__ __forceinline__ float softplus_f(float x) {
  if (x > 20.f) return x;
  if (x < -20.f) return __expf(x);
  return __logf(1.f + __expf(x));
}

// da[n] = g1^(n+1), log-depth
__device__ __forceinline__ void dapow(float g1, float* da) {
  float g2 = g1 * g1, g4 = g2 * g2, g8 = g4 * g4;
  #pragma unroll
  for (int n = 0; n < 16; n++) {
    int e = n + 1;
    float v = (e & 1) ? g1 : 1.f;
    if (e & 2) v *= g2;
    if (e & 4) v *= g4;
    if (e & 8) v *= g8;
    da[n] = v;
  }
}

// ---------------- prep: weight cvt (f32->bf16, x4 vec) + LayerNorm ----------------
__global__ __launch_bounds__(256) void prep_kernel(const float* __restrict__ x,
                                                   const float* __restrict__ g,
                                                   const float* __restrict__ b,
                                                   const float* __restrict__ inw,
                                                   const float* __restrict__ outw,
                                                   const float* __restrict__ xpw,
                                                   ushort_t* __restrict__ xn_bf,
                                                   ushort_t* __restrict__ inw_bf,
                                                   ushort_t* __restrict__ outw_bf,
                                                   ushort_t* __restrict__ xpw_bf) {
  int blk = blockIdx.x;
  if (blk < SEQ) {
    int row = blk;
    const float4* xr = (const float4*)(x + (size_t)row * D_MODEL);
    float4 v = xr[threadIdx.x];
    float s  = v.x + v.y + v.z + v.w;
    float ss = v.x * v.x + v.y * v.y + v.z * v.z + v.w * v.w;
    #pragma unroll
    for (int o = 32; o; o >>= 1) { s += __shfl_down(s, o); ss += __shfl_down(ss, o); }
    __shared__ float sbuf[8], ssbuf[8];
    int wid = threadIdx.x >> 6, lane = threadIdx.x & 63;
    if (lane == 0) { sbuf[wid] = s; ssbuf[wid] = ss; }
    __syncthreads();
    if (threadIdx.x == 0) {
      float t = 0.f, t2 = 0.f;
      for (int i = 0; i < 4; i++) { t += sbuf[i]; t2 += ssbuf[i]; }
      float mu = t / D_MODEL;
      sbuf[4] = mu;
      ssbuf[4] = rsqrtf(t2 / D_MODEL - mu * mu + LN_EPS);
    }
    __syncthreads();
    float mu = sbuf[4], inv = ssbuf[4];
    float4 gv = ((const float4*)g)[threadIdx.x];
    float4 bv = ((const float4*)b)[threadIdx.x];
    ushort_t o4[4];
    o4[0] = f2bf((v.x - mu) * inv * gv.x + bv.x);
    o4[1] = f2bf((v.y - mu) * inv * gv.y + bv.y);
    o4[2] = f2bf((v.z - mu) * inv * gv.z + bv.z);
    o4[3] = f2bf((v.w - mu) * inv * gv.w + bv.w);
    *(ushort4*)&xn_bf[(size_t)row * D_MODEL + threadIdx.x * 4] =
        make_ushort4(o4[0], o4[1], o4[2], o4[3]);
  } else {
    int idx = ((blk - SEQ) * 256 + threadIdx.x) * 4;
    const int n1 = 2 * D_INNER * D_MODEL;
    const int n2 = D_MODEL * D_INNER;
    const int n3 = 64 * D_INNER;
    const float* src; ushort_t* dst; int j;
    if (idx < n1) { src = inw; dst = inw_bf; j = idx; }
    else if (idx < n1 + n2) { src = outw; dst = outw_bf; j = idx - n1; }
    else if (idx < n1 + n2 + n3) {
      j = idx - n1 - n2;
      if (j < 33 * D_INNER) { src = xpw; dst = xpw_bf; }
      else {
        *(ushort4*)&xpw_bf[j] = make_ushort4(0, 0, 0, 0);
        return;
      }
    } else return;
    float4 v = *(const float4*)&src[j];
    *(ushort4*)&dst[j] = make_ushort4(f2bf(v.x), f2bf(v.y), f2bf(v.z), f2bf(v.w));
  }
}

// ---------------- unified pipelined MFMA GEMM, NT layout ----------------
template <int BM, int BN, int KDIM, int EPI, int NBUF, int KSPLIT>
__global__ __launch_bounds__(256, 2) void gemm_pipe(const ushort_t* __restrict__ A,
                                                    const ushort_t* __restrict__ B,
                                                    void* __restrict__ Cout,
                                                    const float* __restrict__ R,
                                                    int N) {
  constexpr int KT = KDIM / 32 / KSPLIT;
  constexpr int K2 = KDIM * 2;
  constexpr int IA = BM / 64, IB = BN / 64;
  constexpr int S  = IA + IB;
  constexpr int W  = (NBUF - 2) * S;
  constexpr int WTM = BM / 2, WTN = BN / 2;
  constexpr int MREP = WTM / 16, NREP = WTN / 16;
  __shared__ __align__(16) ushort_t As[NBUF][BM * 32];
  __shared__ __align__(16) ushort_t Bs[NBUF][BN * 32];

  const int nwg = gridDim.x * gridDim.y;
  int bid = blockIdx.y * gridDim.x + blockIdx.x;
  int swz = (bid & 7) * (nwg >> 3) + (bid >> 3);
  int bn = swz % gridDim.x, bm = swz / gridDim.x;
  int ks = 0;
  if constexpr (KSPLIT > 1) { ks = bn; bn = 0; }
  const int tid = threadIdx.x, wid = tid >> 6, lane = tid & 63;
  const int wm = wid >> 1, wn = wid & 1;
  const int row0A = bm * BM, row0B = bn * BN;
  const size_t kbase = (size_t)ks * KT * 64;

  const char* gA[IA];
  const char* gB[IB];
  #pragma unroll
  for (int i = 0; i < IA; i++) {
    int o = i * 4096 + tid * 16;
    int r = o >> 6, src = (o & 63) ^ ((r & 3) << 4);
    gA[i] = (const char*)A + (size_t)(row0A + r) * K2 + src + kbase;
  }
  #pragma unroll
  for (int i = 0; i < IB; i++) {
    int o = i * 4096 + tid * 16;
    int r = o >> 6, src = (o & 63) ^ ((r & 3) << 4);
    gB[i] = (const char*)B + (size_t)(row0B + r) * K2 + src + kbase;
  }
  const int ldsW = wid * 1024;

  auto STAGE = [&](int bb, int kt) {
    int kb = kt * 64;
    #pragma unroll
    for (int i = 0; i < IA; i++)
      async16((char*)&As[bb][0] + i * 4096 + ldsW, gA[i] + kb);
    #pragma unroll
    for (int i = 0; i < IB; i++)
      async16((char*)&Bs[bb][0] + i * 4096 + ldsW, gB[i] + kb);
  };

  #pragma unroll
  for (int p = 0; p < NBUF - 1; p++) STAGE(p, p);

  int offA[MREP], offB[NREP];
  #pragma unroll
  for (int m = 0; m < MREP; m++) {
    int row = wm * WTM + m * 16 + (lane & 15);
    offA[m] = row * 64 + ((((lane >> 4)) ^ (row & 3)) << 4);
  }
  #pragma unroll
  for (int n = 0; n < NREP; n++) {
    int row = wn * WTN + n * 16 + (lane & 15);
    offB[n] = row * 64 + ((((lane >> 4)) ^ (row & 3)) << 4);
  }

  f32x4 acc[MREP][NREP] = {};
  int cur = 0;
  for (int kt = 0; kt < KT; kt++) {
    if (kt < KT - 1) {
      if constexpr (W == 6)       asm volatile("s_waitcnt vmcnt(6)" ::: "memory");
      else if constexpr (W == 8)  asm volatile("s_waitcnt vmcnt(8)" ::: "memory");
      else if constexpr (W == 12) asm volatile("s_waitcnt vmcnt(12)" ::: "memory");
      else                        asm volatile("s_waitcnt vmcnt(0)" ::: "memory");
    } else {
      asm volatile("s_waitcnt vmcnt(0)" ::: "memory");
    }
    __builtin_amdgcn_s_barrier();
    __builtin_amdgcn_sched_barrier(0);
    const char* Ab = (const char*)&As[cur][0];
    const char* Bb = (const char*)&Bs[cur][0];
    short8 af[MREP], bf[NREP];
    #pragma unroll
    for (int m = 0; m < MREP; m++) af[m] = *(const short8*)(Ab + offA[m]);
    #pragma unroll
    for (int n = 0; n < NREP; n++) bf[n] = *(const short8*)(Bb + offB[n]);
    if (kt + NBUF - 1 < KT) {
      int b2 = cur + NBUF - 1; if (b2 >= NBUF) b2 -= NBUF;
      STAGE(b2, kt + NBUF - 1);
    }
    __builtin_amdgcn_s_setprio(1);
    #pragma unroll
    for (int m = 0; m < MREP; m++)
      #pragma unroll
      for (int n = 0; n < NREP; n++)
        acc[m][n] = __builtin_amdgcn_mfma_f32_16x16x32_bf16(af[m], bf[n], acc[m][n], 0, 0, 0);
    __builtin_amdgcn_s_setprio(0);
    cur++; if (cur == NBUF) cur = 0;
  }

  #pragma unroll
  for (int m = 0; m < MREP; m++)
    #pragma unroll
    for (int n = 0; n < NREP; n++) {
      int r0 = row0A + wm * WTM + m * 16 + ((lane >> 4) << 2);
      int c  = row0B + wn * WTN + n * 16 + (lane & 15);
      #pragma unroll
      for (int q = 0; q < 4; q++) {
        if constexpr (EPI == 0) {
          ((ushort_t*)Cout)[(size_t)(r0 + q) * N + c] = f2bf(acc[m][n][q]);
        } else if constexpr (EPI == 1) {
          size_t idx = (size_t)(r0 + q) * N + c;
          ((float*)Cout)[idx] = acc[m][n][q] + R[idx];
        } else {
          if (c < 33)
            ((float*)Cout)[((size_t)ks * SEQ + r0 + q) * 33 + c] = acc[m][n][q];
        }
      }
    }
}

// ---------------- depthwise causal conv + SiLU, 4 t per block ----------------
__global__ __launch_bounds__(256) void conv_silu_kernel(const ushort_t* __restrict__ xz_bf,
                                                        const float* __restrict__ cw,
                                                        const float* __restrict__ cb,
                                                        ushort_t* __restrict__ xs_bf) {
  const int t0 = blockIdx.x * 4;
  const int d0 = threadIdx.x * 8;
  short8 win[7];
  #pragma unroll
  for (int j = 0; j < 7; j++) {
    int tt = t0 - 3 + j;
    if (tt >= 0) win[j] = *(const short8*)&xz_bf[(size_t)tt * (2 * D_INNER) + d0];
    else         win[j] = (short8)0;
  }
  float4 w[8];
  float  cbv[8];
  #pragma unroll
  for (int j = 0; j < 8; j++) { w[j] = ((const float4*)cw)[d0 + j]; cbv[j] = cb[d0 + j]; }
  #pragma unroll
  for (int q = 0; q < 4; q++) {
    short8 o8;
    #pragma unroll
    for (int j = 0; j < 8; j++) {
      float acc = cbv[j]
                + bf2f((ushort_t)win[q][j])     * w[j].x
                + bf2f((ushort_t)win[q + 1][j]) * w[j].y
                + bf2f((ushort_t)win[q + 2][j]) * w[j].z
                + bf2f((ushort_t)win[q + 3][j]) * w[j].w;
      float sg = 1.f / (1.f + __expf(-acc));
      o8[j] = (short)f2bf(acc * sg);
    }
    *(short8*)&xs_bf[(size_t)(t0 + q) * D_INNER + d0] = o8;
  }
}

// ---------------- scan pass1: 2 d's per thread, xp-partial fold, prefetch, bf16 Hp ----------------
__global__ __launch_bounds__(256) void scan_pass1(const ushort_t* __restrict__ xs_bf,
                                                  const float* __restrict__ xpp,
                                                  const float* __restrict__ dt_w,
                                                  const float* __restrict__ dt_b,
                                                  const float* __restrict__ A_log,
                                                  ushort_t* __restrict__ Hp,
                                                  float* __restrict__ Sd) {
  int c = blockIdx.x;
  int d0 = blockIdx.y * 512 + threadIdx.x;
  __shared__ float Bsh[CLEN][16], drs[CLEN], Ash[16];
  {
    int t = threadIdx.x >> 4, n = threadIdx.x & 15;
    const size_t P = (size_t)SEQ * 33;
    size_t rb = (size_t)(c * CLEN + t) * 33;
    float sB = 0.f;
    #pragma unroll
    for (int k = 0; k < 8; k++) sB += xpp[k * P + rb + 1 + n];
    Bsh[t][n] = sB;
    if (threadIdx.x < CLEN) {
      size_t rr = (size_t)(c * CLEN + threadIdx.x) * 33;
      float sD = 0.f;
      #pragma unroll
      for (int k = 0; k < 8; k++) sD += xpp[k * P + rr];
      drs[threadIdx.x] = sD;
    } else if (threadIdx.x < CLEN + 16) {
      int n2 = threadIdx.x - CLEN;
      Ash[n2] = -__expf(A_log[n2]);
    }
  }
  __syncthreads();
  bool fastA = true;
  #pragma unroll
  for (int n = 0; n < 16; n++) fastA = fastA && (fabsf(Ash[n] + (float)(n + 1)) < 1e-4f * (n + 1));
  float dw[2] = {dt_w[d0], dt_w[d0 + 256]};
  float db[2] = {dt_b[d0], dt_b[d0 + 256]};
  float h[2][16] = {};
  float S[2] = {0.f, 0.f};
  size_t tb = (size_t)(c * CLEN) * D_INNER + d0;
  float xv[2] = {bf2f(xs_bf[tb]), bf2f(xs_bf[tb + 256])};
  for (int t = 0; t < CLEN; t++) {
    float nx[2] = {0.f, 0.f};
    if (t + 1 < CLEN) {
      nx[0] = bf2f(xs_bf[tb + D_INNER]);
      nx[1] = bf2f(xs_bf[tb + D_INNER + 256]);
    }
    float bb[16];
    *(float4*)&bb[0]  = *(const float4*)&Bsh[t][0];
    *(float4*)&bb[4]  = *(const float4*)&Bsh[t][4];
    *(float4*)&bb[8]  = *(const float4*)&Bsh[t][8];
    *(float4*)&bb[12] = *(const float4*)&Bsh[t][12];
    float drt = drs[t];
    #pragma unroll
    for (int u = 0; u < 2; u++) {
      float delta = softplus_f(drt * dw[u] + db[u]);
      S[u] += delta;
      float w = delta * xv[u];
      if (fastA) {
        float da[16];
        dapow(__expf(-delta), da);
        #pragma unroll
        for (int n = 0; n < 16; n++) h[u][n] = da[n] * h[u][n] + w * bb[n];
      } else {
        #pragma unroll
        for (int n = 0; n < 16; n++) h[u][n] = __expf(delta * Ash[n]) * h[u][n] + w * bb[n];
      }
    }
    xv[0] = nx[0]; xv[1] = nx[1];
    tb += D_INNER;
  }
  #pragma unroll
  for (int u = 0; u < 2; u++) {
    int d = d0 + u * 256;
    size_t base = ((size_t)c * D_INNER + d) * 16;
    short8 p0, p1;
    #pragma unroll
    for (int n = 0; n < 8; n++) { p0[n] = (short)f2bf(h[u][n]); p1[n] = (short)f2bf(h[u][8 + n]); }
    *(short8*)&Hp[base] = p0;
    *(short8*)&Hp[base + 8] = p1;
    Sd[(size_t)c * D_INNER + d] = S[u];
  }
}

// ---------------- combine level A (bf16 states) ----------------
__global__ __launch_bounds__(256) void combineA(const ushort_t* __restrict__ Hp,
                                                const float* __restrict__ Sd,
                                                const float* __restrict__ A_log,
                                                ushort_t* __restrict__ Hl,
                                                float* __restrict__ Slocp,
                                                ushort_t* __restrict__ Hgtot,
                                                float* __restrict__ Sgtot) {
  int g = blockIdx.x;
  int idx = blockIdx.y * 256 + threadIdx.x;
  int d = idx >> 4, n = idx & 15;
  float An = -__expf(A_log[n]);
  float h = 0.f, S = 0.f;
  const size_t stride = (size_t)D_INNER * 16;
  #pragma unroll 4
  for (int j = 0; j < GCH; j++) {
    int c = g * GCH + j;
    Hl[(size_t)c * stride + idx] = f2bf(h);
    if (n == 0) Slocp[(size_t)c * D_INNER + d] = S;
    float Sc = Sd[(size_t)c * D_INNER + d];
    float hp = bf2f(Hp[(size_t)c * stride + idx]);
    h = __expf(An * Sc) * h + hp;
    S += Sc;
  }
  Hgtot[(size_t)g * stride + idx] = f2bf(h);
  if (n == 0) Sgtot[(size_t)g * D_INNER + d] = S;
}

// ---------------- combine level B (bf16 states) ----------------
__global__ __launch_bounds__(256) void combineB(const ushort_t* __restrict__ Hgtot,
                                                const float* __restrict__ Sgtot,
                                                const float* __restrict__ A_log,
                                                ushort_t* __restrict__ Ginit) {
  int idx = blockIdx.x * 256 + threadIdx.x;
  int d = idx >> 4, n = idx & 15;
  float An = -__expf(A_log[n]);
  float G = 0.f;
  const size_t stride = (size_t)D_INNER * 16;
  #pragma unroll
  for (int g = 0; g < NGRP; g++) {
    Ginit[(size_t)g * stride + idx] = f2bf(G);
    G = __expf(An * Sgtot[(size_t)g * D_INNER + d]) * G + bf2f(Hgtot[(size_t)g * stride + idx]);
  }
}

// ---------------- scan pass2 + gating -> y_bf ----------------
__global__ __launch_bounds__(256) void scan_pass2(const ushort_t* __restrict__ xs_bf,
                                                  const float* __restrict__ xpp,
                                                  const ushort_t* __restrict__ xz_bf,
                                                  const float* __restrict__ dt_w,
                                                  const float* __restrict__ dt_b,
                                                  const float* __restrict__ A_log,
                                                  const float* __restrict__ Dp,
                                                  const ushort_t* __restrict__ Hl,
                                                  const float* __restrict__ Slocp,
                                                  const ushort_t* __restrict__ Ginit,
                                                  ushort_t* __restrict__ y_bf) {
  int c = blockIdx.x;
  int d0 = blockIdx.y * 512 + threadIdx.x;
  __shared__ float Bsh[CLEN][16], Csh[CLEN][16], drs[CLEN], Ash[16];
  {
    int t = threadIdx.x >> 4, n = threadIdx.x & 15;
    const size_t P = (size_t)SEQ * 33;
    size_t rb = (size_t)(c * CLEN + t) * 33;
    float sB = 0.f, sC = 0.f;
    #pragma unroll
    for (int k = 0; k < 8; k++) {
      sB += xpp[k * P + rb + 1 + n];
      sC += xpp[k * P + rb + 17 + n];
    }
    Bsh[t][n] = sB;
    Csh[t][n] = sC;
    if (threadIdx.x < CLEN) {
      size_t rr = (size_t)(c * CLEN + threadIdx.x) * 33;
      float sD = 0.f;
      #pragma unroll
      for (int k = 0; k < 8; k++) sD += xpp[k * P + rr];
      drs[threadIdx.x] = sD;
    } else if (threadIdx.x < CLEN + 16) {
      int n2 = threadIdx.x - CLEN;
      Ash[n2] = -__expf(A_log[n2]);
    }
  }
  __syncthreads();
  bool fastA = true;
  #pragma unroll
  for (int n = 0; n < 16; n++) fastA = fastA && (fabsf(Ash[n] + (float)(n + 1)) < 1e-4f * (n + 1));
  float dw[2] = {dt_w[d0], dt_w[d0 + 256]};
  float db[2] = {dt_b[d0], dt_b[d0 + 256]};
  float Dd[2] = {Dp[d0], Dp[d0 + 256]};
  int g8 = c >> 4;
  float h[2][16];
  #pragma unroll
  for (int u = 0; u < 2; u++) {
    int d = d0 + u * 256;
    size_t hb = ((size_t)c * D_INNER + d) * 16;
    size_t gb = ((size_t)g8 * D_INNER + d) * 16;
    float Slp = Slocp[(size_t)c * D_INNER + d];
    short8 hl0 = *(const short8*)&Hl[hb];
    short8 hl1 = *(const short8*)&Hl[hb + 8];
    short8 gi0 = *(const short8*)&Ginit[gb];
    short8 gi1 = *(const short8*)&Ginit[gb + 8];
    float hl[16], gi[16];
    #pragma unroll
    for (int n = 0; n < 8; n++) {
      hl[n] = bf2f((ushort_t)hl0[n]); hl[8 + n] = bf2f((ushort_t)hl1[n]);
      gi[n] = bf2f((ushort_t)gi0[n]); gi[8 + n] = bf2f((ushort_t)gi1[n]);
    }
    if (fastA) {
      float pw[16];
      dapow(__expf(-Slp), pw);
      #pragma unroll
      for (int n = 0; n < 16; n++) h[u][n] = hl[n] + pw[n] * gi[n];
    } else {
      #pragma unroll
      for (int n = 0; n < 16; n++) h[u][n] = hl[n] + __expf(Ash[n] * Slp) * gi[n];
    }
  }
  size_t tb = (size_t)(c * CLEN) * D_INNER + d0;
  size_t zb = (size_t)(c * CLEN) * (2 * D_INNER) + D_INNER + d0;
  float xv[2] = {bf2f(xs_bf[tb]), bf2f(xs_bf[tb + 256])};
  float zv[2] = {bf2f(xz_bf[zb]), bf2f(xz_bf[zb + 256])};
  for (int t = 0; t < CLEN; t++) {
    float nx[2] = {0.f, 0.f}, nz[2] = {0.f, 0.f};
    if (t + 1 < CLEN) {
      nx[0] = bf2f(xs_bf[tb + D_INNER]);
      nx[1] = bf2f(xs_bf[tb + D_INNER + 256]);
      nz[0] = bf2f(xz_bf[zb + 2 * D_INNER]);
      nz[1] = bf2f(xz_bf[zb + 2 * D_INNER + 256]);
    }
    float bb[16], cc[16];
    *(float4*)&bb[0]  = *(const float4*)&Bsh[t][0];
    *(float4*)&bb[4]  = *(const float4*)&Bsh[t][4];
    *(float4*)&bb[8]  = *(const float4*)&Bsh[t][8];
    *(float4*)&bb[12] = *(const float4*)&Bsh[t][12];
    *(float4*)&cc[0]  = *(const float4*)&Csh[t][0];
    *(float4*)&cc[4]  = *(const float4*)&Csh[t][4];
    *(float4*)&cc[8]  = *(const float4*)&Csh[t][8];
    *(float4*)&cc[12] = *(const float4*)&Csh[t][12];
    float drt = drs[t];
    size_t ti = (size_t)(c * CLEN + t);
    #pragma unroll
    for (int u = 0; u < 2; u++) {
      float delta = softplus_f(drt * dw[u] + db[u]);
      float w = delta * xv[u];
      float y = 0.f;
      if (fastA) {
        float da[16];
        dapow(__expf(-delta), da);
        #pragma unroll
        for (int n = 0; n < 16; n++) {
          h[u][n] = da[n] * h[u][n] + w * bb[n];
          y += h[u][n] * cc[n];
        }
      } else {
        #pragma unroll
        for (int n = 0; n < 16; n++) {
          h[u][n] = __expf(delta * Ash[n]) * h[u][n] + w * bb[n];
          y += h[u][n] * cc[n];
        }
      }
      float z = zv[u];
      float sz = z / (1.f + __expf(-z));
      float out = (y + xv[u] * Dd[u]) * sz;
      y_bf[ti * D_INNER + d0 + u * 256] = f2bf(out);
    }
    xv[0] = nx[0]; xv[1] = nx[1];
    zv[0] = nz[0]; zv[1] = nz[1];
    tb += D_INNER; zb += 2 * D_INNER;
  }
}

// ---------------- launch ----------------
extern "C" void kernel_launch(void* const* d_in, const int* in_sizes, int n_in,
                              void* d_out, int out_size, void* d_ws, size_t ws_size,
                              hipStream_t stream) {
  const float* x      = (const float*)d_in[0];
  const float* ln_g   = (const float*)d_in[1];
  const float* ln_b   = (const float*)d_in[2];
  const float* in_w   = (const float*)d_in[3];
  const float* conv_w = (const float*)d_in[4];
  const float* conv_b = (const float*)d_in[5];
  const float* xproj_w= (const float*)d_in[6];
  const float* dt_w   = (const float*)d_in[7];
  const float* dt_b   = (const float*)d_in[8];
  const float* A_log  = (const float*)d_in[9];
  const float* Dp     = (const float*)d_in[10];
  const float* out_w  = (const float*)d_in[11];
  float* out = (float*)d_out;

  char* ws = (char*)d_ws;
  size_t off = 0;
  auto alloc = [&](size_t bytes) { char* p = ws + off; off += (bytes + 255) & ~(size_t)255; return p; };
  ushort_t* xz_bf   = (ushort_t*)alloc((size_t)SEQ * 2 * D_INNER * 2);
  ushort_t* xn_bf   = (ushort_t*)alloc((size_t)SEQ * D_MODEL * 2);
  ushort_t* inw_bf  = (ushort_t*)alloc((size_t)2 * D_INNER * D_MODEL * 2);
  ushort_t* outw_bf = (ushort_t*)alloc((size_t)D_MODEL * D_INNER * 2);
  ushort_t* xpw_bf  = (ushort_t*)alloc((size_t)64 * D_INNER * 2);
  ushort_t* xs_bf   = (ushort_t*)alloc((size_t)SEQ * D_INNER * 2);
  float*    xp_part = (float*)   alloc((size_t)8 * SEQ * 33 * 4);
  ushort_t* Hp      = (ushort_t*)alloc((size_t)NCHUNK * D_INNER * 16 * 2);
  ushort_t* Hl      = (ushort_t*)alloc((size_t)NCHUNK * D_INNER * 16 * 2);
  float*    Sd      = (float*)   alloc((size_t)NCHUNK * D_INNER * 4);
  float*    Slocp   = (float*)   alloc((size_t)NCHUNK * D_INNER * 4);
  ushort_t* Hgtot   = (ushort_t*)alloc((size_t)NGRP * D_INNER * 16 * 2);
  float*    Sgtot   = (float*)   alloc((size_t)NGRP * D_INNER * 4);
  ushort_t* Ginit   = (ushort_t*)alloc((size_t)NGRP * D_INNER * 16 * 2);
  ushort_t* y_bf    = (ushort_t*)alloc((size_t)SEQ * D_INNER * 2);
  (void)ws_size;

  const int ncvt4 = (2 * D_INNER * D_MODEL + D_MODEL * D_INNER + 64 * D_INNER) / 4;
  prep_kernel<<<SEQ + (ncvt4 + 255) / 256, 256, 0, stream>>>(
      x, ln_g, ln_b, in_w, out_w, xproj_w, xn_bf, inw_bf, outw_bf, xpw_bf);
  // in_proj: M=2048 N=4096 K=1024 (128x128, NBUF=4, 64KB, 512 blocks = 2/CU)
  gemm_pipe<128, 128, D_MODEL, 0, 4, 1><<<dim3(2 * D_INNER / 128, SEQ / 128), 256, 0, stream>>>(
      xn_bf, inw_bf, xz_bf, nullptr, 2 * D_INNER);
  conv_silu_kernel<<<SEQ / 4, 256, 0, stream>>>(xz_bf, conv_w, conv_b, xs_bf);
  // x_proj: K-split x8, partials consumed directly by the scan passes
  gemm_pipe<64, 64, D_INNER, 3, 6, 8><<<dim3(8, SEQ / 64), 256, 0, stream>>>(
      xs_bf, xpw_bf, xp_part, nullptr, 64);
  // scan
  scan_pass1<<<dim3(NCHUNK, D_INNER / 512), 256, 0, stream>>>(xs_bf, xp_part, dt_w, dt_b, A_log, Hp, Sd);
  combineA<<<dim3(NGRP, D_INNER * 16 / 256), 256, 0, stream>>>(Hp, Sd, A_log, Hl, Slocp, Hgtot, Sgtot);
  combineB<<<D_INNER * 16 / 256, 256, 0, stream>>>(Hgtot, Sgtot, A_log, Ginit);
  scan_pass2<<<dim3(NCHUNK, D_INNER / 512), 256, 0, stream>>>(xs_bf, xp_part, xz_bf, dt_w, dt_b, A_log,
                                                              Dp, Hl, Slocp, Ginit, y_bf);
  // out_proj + residual: M=2048 N=1024 K=2048 (64x64, NBUF=6)
  gemm_pipe<64, 64, D_INNER, 1, 6, 1><<<dim3(D_MODEL / 64, SEQ / 64), 256, 0, stream>>>(
      y_bf, outw_bf, out, x, D_MODEL);
}